// Round 2
// baseline (33.352 us; speedup 1.0000x reference)
//
#include <hip/hip_runtime.h>

#define IN_DIM 2048
#define OUT_DIM 2048
#define LVAL 256

__global__ __launch_bounds__(256) void ulc_kernel(
    const float* __restrict__ input_r, const float* __restrict__ input_i,
    const float* __restrict__ src_r,   const float* __restrict__ src_i,
    const float* __restrict__ rng,
    const int* __restrict__ i1_frwr, const int* __restrict__ i0_frwr,
    const int* __restrict__ i1_frwi, const int* __restrict__ i0_frwi,
    const int* __restrict__ i1_fiwr, const int* __restrict__ i0_fiwr,
    const int* __restrict__ i1_fiwi, const int* __restrict__ i0_fiwi,
    float* __restrict__ out)
{
    __shared__ float rng_s[LVAL];
    __shared__ int redA[4], redB[4];
    const int tid = threadIdx.x;
    rng_s[tid] = rng[tid];            // 256 threads, 256 entries
    __syncthreads();

    const int o = blockIdx.x;
    const size_t base = (size_t)o * IN_DIM + tid * 8;   // 8 columns per thread
    const int cx = tid * 8;

    // ---- issue ALL loads up front (24 x 16B independent) ----
    const float4 sr_0 = *(const float4*)(src_r + base);
    const float4 sr_1 = *(const float4*)(src_r + base + 4);
    const float4 si_0 = *(const float4*)(src_i + base);
    const float4 si_1 = *(const float4*)(src_i + base + 4);
    const float4 xr_0 = *(const float4*)(input_r + cx);
    const float4 xr_1 = *(const float4*)(input_r + cx + 4);
    const float4 xi_0 = *(const float4*)(input_i + cx);
    const float4 xi_1 = *(const float4*)(input_i + cx + 4);
    const int4 a1_0 = *(const int4*)(i1_frwr + base);
    const int4 a1_1 = *(const int4*)(i1_frwr + base + 4);
    const int4 a0_0 = *(const int4*)(i0_frwr + base);
    const int4 a0_1 = *(const int4*)(i0_frwr + base + 4);
    const int4 b1_0 = *(const int4*)(i1_frwi + base);
    const int4 b1_1 = *(const int4*)(i1_frwi + base + 4);
    const int4 b0_0 = *(const int4*)(i0_frwi + base);
    const int4 b0_1 = *(const int4*)(i0_frwi + base + 4);
    const int4 c1_0 = *(const int4*)(i1_fiwr + base);
    const int4 c1_1 = *(const int4*)(i1_fiwr + base + 4);
    const int4 c0_0 = *(const int4*)(i0_fiwr + base);
    const int4 c0_1 = *(const int4*)(i0_fiwr + base + 4);
    const int4 d1_0 = *(const int4*)(i1_fiwi + base);
    const int4 d1_1 = *(const int4*)(i1_fiwi + base + 4);
    const int4 d0_0 = *(const int4*)(i0_fiwi + base);
    const int4 d0_1 = *(const int4*)(i0_fiwi + base + 4);

    int accA = 0, accB = 0;

    #define ELEM(k, e)                                                           \
    {                                                                            \
        const float sr = sr_##k.e, si = si_##k.e;                                \
        const bool xr = xr_##k.e > 0.5f;                                         \
        const bool xi = xi_##k.e > 0.5f;                                         \
        const int frwr = xr  ? (sr > rng_s[a1_##k.e & 255]) : !(sr > rng_s[a0_##k.e & 255]); \
        const int frwi = xr  ? (si > rng_s[b1_##k.e & 255]) : !(si > rng_s[b0_##k.e & 255]); \
        const int fiwr = xi  ? (sr > rng_s[c1_##k.e & 255]) : !(sr > rng_s[c0_##k.e & 255]); \
        const int fiwi = !xi ? (si > rng_s[d1_##k.e & 255]) : !(si > rng_s[d0_##k.e & 255]); \
        accA += frwr + fiwi;                                                     \
        accB += frwi + fiwr;                                                     \
    }
    ELEM(0, x) ELEM(0, y) ELEM(0, z) ELEM(0, w)
    ELEM(1, x) ELEM(1, y) ELEM(1, z) ELEM(1, w)
    #undef ELEM

    // wave (64-lane) reduction
    #pragma unroll
    for (int off = 32; off > 0; off >>= 1) {
        accA += __shfl_down(accA, off);
        accB += __shfl_down(accB, off);
    }
    const int wid = tid >> 6;
    if ((tid & 63) == 0) { redA[wid] = accA; redB[wid] = accB; }
    __syncthreads();
    if (tid == 0) {
        const int sA = redA[0] + redA[1] + redA[2] + redA[3];
        const int sB = redB[0] + redB[1] + redB[2] + redB[3];
        out[o]           = (sA >= 2048) ? 1.0f : 0.0f;  // acc - 2047.5 > 0
        out[OUT_DIM + o] = (sB >= 2048) ? 1.0f : 0.0f;
    }
}

extern "C" void kernel_launch(void* const* d_in, const int* in_sizes, int n_in,
                              void* d_out, int out_size, void* d_ws, size_t ws_size,
                              hipStream_t stream) {
    const float* input_r = (const float*)d_in[0];
    const float* input_i = (const float*)d_in[1];
    const float* src_r   = (const float*)d_in[2];
    const float* src_i   = (const float*)d_in[3];
    const float* rng     = (const float*)d_in[4];
    const int* i1_frwr = (const int*)d_in[5];
    const int* i0_frwr = (const int*)d_in[6];
    const int* i1_frwi = (const int*)d_in[7];
    const int* i0_frwi = (const int*)d_in[8];
    const int* i1_fiwr = (const int*)d_in[9];
    const int* i0_fiwr = (const int*)d_in[10];
    const int* i1_fiwi = (const int*)d_in[11];
    const int* i0_fiwi = (const int*)d_in[12];
    float* out = (float*)d_out;

    ulc_kernel<<<dim3(OUT_DIM), dim3(256), 0, stream>>>(
        input_r, input_i, src_r, src_i, rng,
        i1_frwr, i0_frwr, i1_frwi, i0_frwi,
        i1_fiwr, i0_fiwr, i1_fiwi, i0_fiwi,
        out);
}